// Round 4
// baseline (3154.345 us; speedup 1.0000x reference)
//
#include <hip/hip_runtime.h>
#include <math.h>

#define TB 512
#define NBATCH 32
#define TT 256
#define DD 256

typedef float f32x4 __attribute__((ext_vector_type(4)));

// ---------------- workspace layout (float offsets) ----------------
#define WS_WF   0u            // fused Wf = composer_W @ writer_W  [512][1024]
#define WS_BF   524288u       // fused bias [1024]
#define WS_HP   525312u       // h publish, double-buffered [2][32][256]
#define WS_PAR  541696u       // partials [32 batches][8 slices][260] (256 P + max + sum)
#define PS      260
#define WS_WHP  608256u       // wh publish [32][256]
#define WS_BAR  616448u       // barrier flags + legacy counters (ints)
#define WS_FLOATS 624704u

// ---------------- LDS layout (float offsets) ----------------
// ak(k) = k + 4*(k/128): 4-float pad every 128 -> region bases (0/256/512)
// stay 16B-aligned and q-subchunks of 64 floats are contiguous.
#define O_WW    0        // writer weights [16 cols][792]
#define S_WW    792
#define O_RW    12672    // reader weights [16 cols][524]
#define S_RW    524
#define O_MEM   21056    // mem slice [32 rows][260]
#define S_MEM   260
#define O_WACT  29376    // writer act [8 bl][792]: [o|m_rt|wh] at ak positions
#define S_WACT  792
#define O_RACT  35712    // reader act [8 bl][524]: [x|h] at ak positions
#define S_RACT  524
#define O_WZ    39904    // [8][20]
#define O_RZ    40064    // [8][20]
#define O_SS    40224    // [32] raw scores
#define O_SE    40256    // [32] exp(s - local max)
#define O_WC    40288    // [32] writer c
#define O_RC    40320    // [32] reader c
#define O_WB    40352    // [16] writer bias slice
#define O_RB    40368    // [16] reader bias slice
#define O_RJ    40384    // [8 bl][8 j] softmax combine weights
#define O_MS    40448    // [8 bl][8 j][2] (max,sum) staging
#define LDS_FLOATS 40576
#define DYN_LDS_BYTES (LDS_FLOATS*4)   // 162,304 B  (<= 163,840)

__device__ __forceinline__ float hsig(float x) { return fminf(fmaxf(0.2f*x + 0.5f, 0.f), 1.f); }
__device__ __forceinline__ int ak(int k) { return k + 4*(k/128); }

// cross-WG scalar ops: relaxed agent-scope atomics (L3 coherence point, no fences)
__device__ __forceinline__ void gst(float* p, float v) {
  __hip_atomic_store(p, v, __ATOMIC_RELAXED, __HIP_MEMORY_SCOPE_AGENT);
}
__device__ __forceinline__ float gld(const float* p) {
  return __hip_atomic_load(p, __ATOMIC_RELAXED, __HIP_MEMORY_SCOPE_AGENT);
}
__device__ __forceinline__ void gst4(float* p, f32x4 v) {
  asm volatile("global_store_dwordx4 %0, %1, off sc0 sc1" :: "v"(p), "v"(v) : "memory");
}

// Flag-array barrier: each WG owns one 128B line; no same-line RMW hot spot.
// Flags start as poison (0xAAAAAAAA < 0), phases are >=1, compare is >=,
// so no zero-init round is needed.
__device__ __forceinline__ void bar_arrive(int* myflag, int phase) {
  asm volatile("s_waitcnt vmcnt(0) lgkmcnt(0)" ::: "memory");  // all publishes at L3
  __syncthreads();                                             // ...for every thread
  if (threadIdx.x == 0)
    __hip_atomic_store(myflag, phase, __ATOMIC_RELAXED, __HIP_MEMORY_SCOPE_AGENT);
}
__device__ __forceinline__ void bar_wait(int* flags, int phase) {
  if (threadIdx.x < 64) {   // 64 lanes poll 64 flags in parallel (one load/round)
    int sp = 0;
    for (;;) {
      const int v = __hip_atomic_load(&flags[threadIdx.x*32], __ATOMIC_RELAXED,
                                      __HIP_MEMORY_SCOPE_AGENT);
      if (__all(v >= phase)) break;
      if (++sp > (1 << 16)) break;   // fail loud (wrong answer), never hang
    }
  }
  __syncthreads();
}
// fenced barrier — used ONCE after the weight fold (normal stores/loads of Wf)
__device__ __forceinline__ void barrier_fenced(int* cnt, int target) {
  __syncthreads();
  if (threadIdx.x == 0) {
    __threadfence();
    __hip_atomic_fetch_add(cnt, 1, __ATOMIC_RELAXED, __HIP_MEMORY_SCOPE_AGENT);
    int sp = 0;
    while (__hip_atomic_load(cnt, __ATOMIC_RELAXED, __HIP_MEMORY_SCOPE_AGENT) < target) {
      if (++sp > (1 << 20)) break;
    }
    __threadfence();
  }
  __syncthreads();
}

__global__ void __launch_bounds__(TB) nse_kernel(
    const float* __restrict__ x,
    const float* __restrict__ rW, const float* __restrict__ rU, const float* __restrict__ rb,
    const float* __restrict__ wW, const float* __restrict__ wU, const float* __restrict__ wb,
    const float* __restrict__ cW, const float* __restrict__ cb,
    float* __restrict__ out, float* __restrict__ ws)
{
  extern __shared__ float sm[];
  const int tid = threadIdx.x;
  const int w = blockIdx.x;
  const int g = w >> 6;        // 4 groups x 64 members; group owns batches 8g..8g+7
  const int m = w & 63;        // member owns d-cols [4m,4m+4) for all 8 batches,
                               // and mem rows [32*(m&7), +32) of batch (m>>3)
  const int b0 = g * 8;
  const int blm = m >> 3;      // my mem batch (local)
  const int isl = m & 7;       // my mem t-slice
  const int bmy = b0 + blm;

  float* Wf   = ws + WS_WF;
  float* bfv  = ws + WS_BF;
  float* hpub = ws + WS_HP;
  float* par  = ws + WS_PAR;
  float* whp  = ws + WS_WHP;
  int*   bars = (int*)(ws + WS_BAR);
  int* flg    = &bars[g*2048];         // group's 64 flag lines
  int* myflag = &bars[g*2048 + m*32];
  int* lcnt   = &bars[8192];           // legacy fold counter
  int* magic  = &bars[8192 + 32];

  // ---- legacy counter init (ws poisoned 0xAA every launch) ----
  if (w == 0 && tid == 0) {
    __hip_atomic_store(lcnt, 0, __ATOMIC_RELAXED, __HIP_MEMORY_SCOPE_AGENT);
    __hip_atomic_store(magic, 1357911, __ATOMIC_RELEASE, __HIP_MEMORY_SCOPE_AGENT);
  }
  if (tid == 0) {
    int sp = 0;
    while (__hip_atomic_load(magic, __ATOMIC_ACQUIRE, __HIP_MEMORY_SCOPE_AGENT) != 1357911) {
      if (++sp > (1 << 20)) break;
    }
  }
  __syncthreads();

  // ================= fold: Wf = cW @ wW (32k x 64n per WG), bf = cb@wW + wb =================
  {
    const int kt = w >> 4, nt = w & 15;
    const int r = tid >> 4, c4 = (tid & 15) * 4;
    float a0 = 0.f, a1 = 0.f, a2 = 0.f, a3 = 0.f;
    for (int jc = 0; jc < 512; jc += 32) {
      for (int u = tid; u < 1024; u += TB) {
        int rr = u >> 5, jj = u & 31;
        sm[rr*33 + jj] = cW[(32*kt + rr)*512 + jc + jj];
      }
      {
        int jj = tid >> 4, cc = (tid & 15) * 4;
        const f32x4 v = *(const f32x4*)&wW[(jc + jj)*1024 + 64*nt + cc];
        float* d = &sm[1056 + jj*68 + cc];
        d[0] = v.x; d[1] = v.y; d[2] = v.z; d[3] = v.w;
      }
      __syncthreads();
      #pragma unroll 8
      for (int j = 0; j < 32; j++) {
        const float a = sm[r*33 + j];
        const float* wv = &sm[1056 + j*68 + c4];
        a0 += a*wv[0]; a1 += a*wv[1]; a2 += a*wv[2]; a3 += a*wv[3];
      }
      __syncthreads();
    }
    float* d = &Wf[(32*kt + r)*1024 + 64*nt + c4];
    d[0] = a0; d[1] = a1; d[2] = a2; d[3] = a3;
  }
  if (w >= 16 && w < 32) {   // bias fold
    __syncthreads();
    const int base = (w - 16) * 64;
    const int c = tid & 63, jq = tid >> 6;
    float p = 0.f;
    for (int j = 64*jq; j < 64*jq + 64; j++) p += cb[j] * wW[j*1024 + base + c];
    sm[jq*68 + c] = p;
    __syncthreads();
    if (tid < 64) {
      float s = wb[base + tid];
      for (int j = 0; j < 8; j++) s += sm[j*68 + tid];
      bfv[base + tid] = s;
    }
  }
  barrier_fenced(lcnt, 256);

  // ================= init: stage weights, mem, x0, biases; zero state =================
  for (int u = tid; u < 3072; u += TB) {        // writer [Wf|wU] col slice
    const int k = u >> 2, gate = u & 3;
    const float* sp = (k < 512) ? &Wf[(size_t)k*1024 + gate*256 + 4*m]
                                : &wU[(size_t)(k-512)*1024 + gate*256 + 4*m];
    const f32x4 v = *(const f32x4*)sp;
    const int ik = ak(k);
    sm[O_WW + (gate*4+0)*S_WW + ik] = v.x;
    sm[O_WW + (gate*4+1)*S_WW + ik] = v.y;
    sm[O_WW + (gate*4+2)*S_WW + ik] = v.z;
    sm[O_WW + (gate*4+3)*S_WW + ik] = v.w;
  }
  for (int u = tid; u < 2048; u += TB) {        // reader [rW|rU] col slice
    const int k = u >> 2, gate = u & 3;
    const float* sp = (k < 256) ? &rW[(size_t)k*1024 + gate*256 + 4*m]
                                : &rU[(size_t)(k-256)*1024 + gate*256 + 4*m];
    const f32x4 v = *(const f32x4*)sp;
    const int ik = ak(k);
    sm[O_RW + (gate*4+0)*S_RW + ik] = v.x;
    sm[O_RW + (gate*4+1)*S_RW + ik] = v.y;
    sm[O_RW + (gate*4+2)*S_RW + ik] = v.z;
    sm[O_RW + (gate*4+3)*S_RW + ik] = v.w;
  }
  for (int u = tid; u < 2048; u += TB) {        // mem slice init = x[bmy][32*isl..][:]
    const int r = u >> 6, d4 = (u & 63) * 4;
    *(f32x4*)&sm[O_MEM + r*S_MEM + d4] =
        *(const f32x4*)&x[((size_t)bmy*TT + 32*isl + r)*DD + d4];
  }
  for (int u = tid; u < LDS_FLOATS - O_WACT; u += TB) sm[O_WACT + u] = 0.f;
  {   // x_0
    const int bl = tid >> 6, d4 = (tid & 63) * 4;
    *(f32x4*)&sm[O_RACT + bl*S_RACT + ak(d4)] =
        *(const f32x4*)&x[(size_t)(b0+bl)*TT*DD + d4];
  }
  if (tid < 16) {
    const int gate = tid >> 2, dl = tid & 3;
    sm[O_WB + tid] = bfv[gate*256 + 4*m + dl];
    sm[O_RB + tid] = rb[gate*256 + 4*m + dl];
  }
  __syncthreads();

  // thread roles for the GEMVs (shared by reader + writer)
  const int q  = tid & 3;
  const int cl = ((tid >> 4) & 3) + 4 * (tid >> 7);
  const int bl8 = ((tid >> 2) & 3) + 4 * ((tid >> 6) & 1);
  const int qo = (q >> 1) * 132 + (q & 1) * 64;   // q-subchunk offset inside a region

  // ================= merged loop: reader step s (s<=255), writer step t=s-1 (s>=1) =================
  int bphase = 0;
  for (int s = 0; s <= TT; s++) {
    // ---- stage h_{s-1}, wh_{s-2} (one L3 round trip) ----
    {
      const int bl = tid >> 6, d4 = (tid & 63) * 4;
      f32x4 vh, vw;
      const float* ph = &hpub[(size_t)((s+1)&1)*8192 + (b0+bl)*256 + d4];
      const float* pw = &whp[(b0+bl)*256 + d4];
      asm volatile(
        "global_load_dwordx4 %0, %2, off sc0 sc1\n\t"
        "global_load_dwordx4 %1, %3, off sc0 sc1\n\t"
        "s_waitcnt vmcnt(0)"
        : "=&v"(vh), "=&v"(vw) : "v"(ph), "v"(pw) : "memory");
      if (s >= 1) {
        *(f32x4*)&sm[O_RACT + bl*S_RACT + ak(256 + d4)] = vh;   // reader h-in / W1 o
        *(f32x4*)&sm[O_WACT + bl*S_WACT + ak(d4)]       = vh;   // writer GEMV o
      }
      if (s >= 2)
        *(f32x4*)&sm[O_WACT + bl*S_WACT + ak(512 + d4)] = vw;   // writer GEMV wh + mem upd
    }
    __syncthreads();

    // ---- W1 (s>=1): fused lazy mem-update + scores vs o ----
    if (s >= 1) {
      const int r = tid >> 4, tk = tid & 15;
      float* mrow = &sm[O_MEM + r*S_MEM + 16*tk];
      const float* orow = &sm[O_RACT + blm*S_RACT + ak(256 + 16*tk)];
      float acc = 0.f;
      if (s >= 2) {
        const float zr = sm[O_SE + r] * sm[O_RJ + blm*8 + isl];
        const float omz = 1.f - zr;
        const float* hrow = &sm[O_WACT + blm*S_WACT + ak(512 + 16*tk)];
        #pragma unroll
        for (int i2 = 0; i2 < 16; i2 += 4) {
          f32x4 mv = *(f32x4*)(mrow + i2);
          const f32x4 hv = *(const f32x4*)(hrow + i2);
          const f32x4 ov = *(const f32x4*)(orow + i2);
          mv.x = mv.x*omz + hv.x*zr;  mv.y = mv.y*omz + hv.y*zr;
          mv.z = mv.z*omz + hv.z*zr;  mv.w = mv.w*omz + hv.w*zr;
          *(f32x4*)(mrow + i2) = mv;
          acc += mv.x*ov.x + mv.y*ov.y + mv.z*ov.z + mv.w*ov.w;
        }
      } else {
        #pragma unroll
        for (int i2 = 0; i2 < 16; i2 += 4) {
          const f32x4 mv = *(const f32x4*)(mrow + i2);
          const f32x4 ov = *(const f32x4*)(orow + i2);
          acc += mv.x*ov.x + mv.y*ov.y + mv.z*ov.z + mv.w*ov.w;
        }
      }
      acc += __shfl_xor(acc, 1, 64); acc += __shfl_xor(acc, 2, 64);
      acc += __shfl_xor(acc, 4, 64); acc += __shfl_xor(acc, 8, 64);
      if (tk == 0) sm[O_SS + r] = acc;
    }
    __syncthreads();
    if (s >= 1 && tid < 32) {   // local softmax over my 32 rows
      const float sc = sm[O_SS + tid];
      float mx = sc;
      mx = fmaxf(mx, __shfl_xor(mx, 1, 64)); mx = fmaxf(mx, __shfl_xor(mx, 2, 64));
      mx = fmaxf(mx, __shfl_xor(mx, 4, 64)); mx = fmaxf(mx, __shfl_xor(mx, 8, 64));
      mx = fmaxf(mx, __shfl_xor(mx, 16, 64));
      const float e = __expf(sc - mx);
      float su = e;
      su += __shfl_xor(su, 1, 64); su += __shfl_xor(su, 2, 64); su += __shfl_xor(su, 4, 64);
      su += __shfl_xor(su, 8, 64); su += __shfl_xor(su, 16, 64);
      sm[O_SE + tid] = e;
      if (tid == 0) {
        gst(&par[((size_t)bmy*8 + isl)*PS + 256], mx);
        gst(&par[((size_t)bmy*8 + isl)*PS + 257], su);
      }
    }
    __syncthreads();
    // ---- W2 (s>=1): P_isl[d] = sum_r e_r mem[r][d]; vector publish ----
    if (s >= 1) {
      const int dblk = tid >> 3, rh = tid & 7;
      f32x4 p; p.x = 0.f; p.y = 0.f; p.z = 0.f; p.w = 0.f;
      #pragma unroll
      for (int i = 0; i < 4; i++) {
        const int rr = 4*rh + i;
        const float e = sm[O_SE + rr];
        const f32x4 mv = *(const f32x4*)&sm[O_MEM + rr*S_MEM + 4*dblk];
        p.x += e*mv.x; p.y += e*mv.y; p.z += e*mv.z; p.w += e*mv.w;
      }
      p.x += __shfl_xor(p.x,1,64); p.x += __shfl_xor(p.x,2,64); p.x += __shfl_xor(p.x,4,64);
      p.y += __shfl_xor(p.y,1,64); p.y += __shfl_xor(p.y,2,64); p.y += __shfl_xor(p.y,4,64);
      p.z += __shfl_xor(p.z,1,64); p.z += __shfl_xor(p.z,2,64); p.z += __shfl_xor(p.z,4,64);
      p.w += __shfl_xor(p.w,1,64); p.w += __shfl_xor(p.w,2,64); p.w += __shfl_xor(p.w,4,64);
      if (rh == 0) gst4(&par[((size_t)bmy*8 + isl)*PS + 4*dblk], p);
    }
    ++bphase; bar_arrive(myflag, bphase);      // ---- barrier A arrive (partials) ----

    // ---- slack: reader GEMV + gates + h publish; writer o/wh-segment pre-dot ----
    float accw = 0.f;
    if (s <= TT-1) {
      const float* wr = &sm[O_RW + cl*S_RW + 132*q];
      const float* ar = &sm[O_RACT + bl8*S_RACT + 132*q];
      float acc = 0.f;
      #pragma unroll
      for (int kk = 0; kk < 128; kk += 4) {
        const f32x4 wv = *(const f32x4*)(wr + kk);
        const f32x4 av = *(const f32x4*)(ar + kk);
        acc += wv.x*av.x + wv.y*av.y + wv.z*av.z + wv.w*av.w;
      }
      acc += __shfl_xor(acc, 1, 64);
      acc += __shfl_xor(acc, 2, 64);
      if (q == 0) sm[O_RZ + bl8*20 + cl] = acc + sm[O_RB + cl];
    }
    if (s >= 1) {   // writer pre-dot: regions R0 (o, base 0) and R2 (wh, base 528)
      const float* wr = &sm[O_WW + cl*S_WW];
      const float* ar = &sm[O_WACT + bl8*S_WACT];
      #pragma unroll
      for (int kk = 0; kk < 64; kk += 4) {
        const f32x4 w0 = *(const f32x4*)(wr + qo + kk);
        const f32x4 a0 = *(const f32x4*)(ar + qo + kk);
        const f32x4 w2 = *(const f32x4*)(wr + 528 + qo + kk);
        const f32x4 a2 = *(const f32x4*)(ar + 528 + qo + kk);
        accw += w0.x*a0.x + w0.y*a0.y + w0.z*a0.z + w0.w*a0.w;
        accw += w2.x*a2.x + w2.y*a2.y + w2.z*a2.z + w2.w*a2.w;
      }
    }
    __syncthreads();
    if (s <= TT-1 && tid < 32) {
      const int bl = tid >> 2, dl = tid & 3;
      const float zi = sm[O_RZ + bl*20 + dl];
      const float zf = sm[O_RZ + bl*20 + 4 + dl];
      const float zg = sm[O_RZ + bl*20 + 8 + dl];
      const float zo = sm[O_RZ + bl*20 + 12 + dl];
      const float cn = hsig(zf)*sm[O_RC + tid] + hsig(zi)*tanhf(zg);
      sm[O_RC + tid] = cn;
      gst(&hpub[(size_t)(s&1)*8192 + (b0+bl)*256 + 4*m + dl], hsig(zo)*tanhf(cn));
    }
    bar_wait(flg, bphase);                     // ---- barrier A wait ----

    if (s >= 1) {
      // ---- combine: ONE L3 round trip for 8 P-slices + (max,sum) ----
      const int bl = tid >> 6, d4 = (tid & 63) * 4;
      f32x4 v0,v1,v2,v3,v4,v5,v6,v7;
      float msv;
      {
        const float* p0 = &par[((size_t)(b0+bl)*8 + 0)*PS + d4];
        const float* p4 = p0 + 4*PS;
        const int idx = tid & 127;
        const float* msp = &par[((size_t)(b0 + (idx>>4))*8 + ((idx>>1)&7))*PS + 256 + (idx&1)];
        asm volatile(
          "global_load_dwordx4 %0, %9, off sc0 sc1\n\t"
          "global_load_dwordx4 %1, %9, off offset:1040 sc0 sc1\n\t"
          "global_load_dwordx4 %2, %9, off offset:2080 sc0 sc1\n\t"
          "global_load_dwordx4 %3, %9, off offset:3120 sc0 sc1\n\t"
          "global_load_dwordx4 %4, %10, off sc0 sc1\n\t"
          "global_load_dwordx4 %5, %10, off offset:1040 sc0 sc1\n\t"
          "global_load_dwordx4 %6, %10, off offset:2080 sc0 sc1\n\t"
          "global_load_dwordx4 %7, %10, off offset:3120 sc0 sc1\n\t"
          "global_load_dword   %8, %11, off sc0 sc1\n\t"
          "s_waitcnt vmcnt(0)"
          : "=&v"(v0),"=&v"(v1),"=&v"(v2),"=&v"(v3),
            "=&v"(v4),"=&v"(v5),"=&v"(v6),"=&v"(v7),"=&v"(msv)
          : "v"(p0), "v"(p4), "v"(msp) : "memory");
      }
      if (tid < 128) sm[O_MS + tid] = msv;   // [bl][j][h2] layout matches msp index
      __syncthreads();
      if (tid < 8) {
        const int bl2 = tid;
        float M = sm[O_MS + bl2*16];
        for (int j = 1; j < 8; j++) M = fmaxf(M, sm[O_MS + bl2*16 + 2*j]);
        float tot = 0.f, f0[8];
        for (int j = 0; j < 8; j++) {
          f0[j] = __expf(sm[O_MS + bl2*16 + 2*j] - M);
          tot += f0[j] * sm[O_MS + bl2*16 + 2*j + 1];
        }
        const float inv = 1.f / tot;
        for (int j = 0; j < 8; j++) sm[O_RJ + bl2*8 + j] = f0[j]*inv;
      }
      __syncthreads();
      {
        const float* rj = &sm[O_RJ + bl*8];
        f32x4 a;
        a.x = rj[0]*v0.x + rj[1]*v1.x + rj[2]*v2.x + rj[3]*v3.x
            + rj[4]*v4.x + rj[5]*v5.x + rj[6]*v6.x + rj[7]*v7.x;
        a.y = rj[0]*v0.y + rj[1]*v1.y + rj[2]*v2.y + rj[3]*v3.y
            + rj[4]*v4.y + rj[5]*v5.y + rj[6]*v6.y + rj[7]*v7.y;
        a.z = rj[0]*v0.z + rj[1]*v1.z + rj[2]*v2.z + rj[3]*v3.z
            + rj[4]*v4.z + rj[5]*v5.z + rj[6]*v6.z + rj[7]*v7.z;
        a.w = rj[0]*v0.w + rj[1]*v1.w + rj[2]*v2.w + rj[3]*v3.w
            + rj[4]*v4.w + rj[5]*v5.w + rj[6]*v6.w + rj[7]*v7.w;
        *(f32x4*)&sm[O_WACT + bl*S_WACT + ak(256 + d4)] = a;
      }
      __syncthreads();
      // ---- writer m_rt-segment dot (R1, base 264) + finish gates ----
      {
        const float* wr = &sm[O_WW + cl*S_WW + 264 + qo];
        const float* ar = &sm[O_WACT + bl8*S_WACT + 264 + qo];
        #pragma unroll
        for (int kk = 0; kk < 64; kk += 4) {
          const f32x4 wv = *(const f32x4*)(wr + kk);
          const f32x4 av = *(const f32x4*)(ar + kk);
          accw += wv.x*av.x + wv.y*av.y + wv.z*av.z + wv.w*av.w;
        }
        accw += __shfl_xor(accw, 1, 64);
        accw += __shfl_xor(accw, 2, 64);
        if (q == 0) sm[O_WZ + bl8*20 + cl] = accw + sm[O_WB + cl];
      }
      __syncthreads();
      if (tid < 32) {   // writer LSTM update + publish wh (or out at last step)
        const int bl2 = tid >> 2, dl = tid & 3;
        const float zi = sm[O_WZ + bl2*20 + dl];
        const float zf = sm[O_WZ + bl2*20 + 4 + dl];
        const float zg = sm[O_WZ + bl2*20 + 8 + dl];
        const float zo = sm[O_WZ + bl2*20 + 12 + dl];
        const float cn = hsig(zf)*sm[O_WC + tid] + hsig(zi)*tanhf(zg);
        sm[O_WC + tid] = cn;
        const float hn = hsig(zo)*tanhf(cn);
        if (s == TT) out[(b0+bl2)*256 + 4*m + dl] = hn;
        else         gst(&whp[(b0+bl2)*256 + 4*m + dl], hn);
      }
    }
    if (s == TT) break;                        // out stored; nothing left to sync
    ++bphase; bar_arrive(myflag, bphase);      // ---- barrier B (wh + h_s) ----
    if (s <= TT-2) {   // slack: stage x_{s+1} (plain loads, no cross-WG dependency)
      const int bl = tid >> 6, d4 = (tid & 63) * 4;
      *(f32x4*)&sm[O_RACT + bl*S_RACT + ak(d4)] =
          *(const f32x4*)&x[((size_t)(b0+bl)*TT + s + 1)*DD + d4];
    }
    bar_wait(flg, bphase);
  }
}

extern "C" void kernel_launch(void* const* d_in, const int* in_sizes, int n_in,
                              void* d_out, int out_size, void* d_ws, size_t ws_size,
                              hipStream_t stream) {
  (void)in_sizes; (void)n_in;
  if (ws_size < (size_t)WS_FLOATS * 4u) {   // loud failure instead of corruption
    hipMemsetAsync(d_out, 0, (size_t)out_size * 4u, stream);
    return;
  }
  const float* x  = (const float*)d_in[0];
  const float* rW = (const float*)d_in[1];
  const float* rU = (const float*)d_in[2];
  const float* rb = (const float*)d_in[3];
  const float* wW = (const float*)d_in[4];
  const float* wU = (const float*)d_in[5];
  const float* wb = (const float*)d_in[6];
  const float* cW = (const float*)d_in[7];
  const float* cb = (const float*)d_in[8];
  float* out = (float*)d_out;
  float* ws  = (float*)d_ws;

  hipFuncSetAttribute((const void*)nse_kernel,
                      hipFuncAttributeMaxDynamicSharedMemorySize, DYN_LDS_BYTES);

  void* args[] = { (void*)&x, (void*)&rW, (void*)&rU, (void*)&rb,
                   (void*)&wW, (void*)&wU, (void*)&wb, (void*)&cW, (void*)&cb,
                   (void*)&out, (void*)&ws };
  hipError_t err = hipLaunchCooperativeKernel((const void*)nse_kernel,
                                              dim3(256), dim3(TB), args,
                                              DYN_LDS_BYTES, stream);
  if (err != hipSuccess) {
    nse_kernel<<<dim3(256), dim3(TB), DYN_LDS_BYTES, stream>>>(
        x, rW, rU, rb, wW, wU, wb, cW, cb, out, ws);
  }
}

// Round 5
// 2980.324 us; speedup vs baseline: 1.0584x; 1.0584x over previous
//
#include <hip/hip_runtime.h>
#include <math.h>

#define TB 512
#define NBATCH 32
#define TT 256
#define DD 256

typedef float f32x4 __attribute__((ext_vector_type(4)));

// ---------------- workspace layout (float offsets) ----------------
#define WS_WF   0u            // fused Wf = composer_W @ writer_W  [512][1024]
#define WS_BF   524288u       // fused bias [1024]
#define WS_HP   525312u       // h publish, double-buffered [2][32][256]
#define WS_PAR  541696u       // partials [32 batches][8 slices][260] (256 P + max + sum)
#define PS      260
#define WS_WHP  608256u       // wh publish [32][256]
#define WS_BAR  616448u       // tag words + legacy fold counter (ints)
#define WS_FLOATS 624704u
// int offsets inside WS_BAR: tagsA [4][64][16] = 4096; tagsB +4096; lcnt 8192; magic 8224

// ---------------- LDS layout (float offsets) ----------------
#define O_WW    0        // writer weights [16 cols][784]  (akw: pad 4 per 192)
#define S_WW    784
#define O_RW    12544    // reader weights [16 cols][524]  (akr: pad 4 per 128)
#define S_RW    524
#define O_MEM   20928    // mem slice [32 rows][260]
#define S_MEM   260
#define O_WACT  29248    // writer act [8 bl][792]: [o|m_rt|wh] at akw positions
#define S_WACT  792
#define O_RACT  35584    // reader act [8 bl][524]: [x|h] at akr positions
#define S_RACT  524
#define O_WZ    39776    // [8][20]
#define O_RZ    39936    // [8][20]
#define O_SS    40096    // [32] raw scores
#define O_SE    40128    // [32] exp(s - local max)
#define O_WC    40160    // [32] writer c
#define O_RC    40192    // [32] reader c
#define O_WB    40224    // [16] writer bias slice
#define O_RB    40240    // [16] reader bias slice
#define O_RJ    40256    // [8 bl][8 j] softmax combine weights
#define O_MS    40320    // [8 bl][8 j][2] (max,sum) staging
#define LDS_FLOATS 40448
#define DYN_LDS_BYTES (LDS_FLOATS*4)   // 161,792 B (<= 163,840)

__device__ __forceinline__ float hsig(float x) { return fminf(fmaxf(0.2f*x + 0.5f, 0.f), 1.f); }
__device__ __forceinline__ float ftanh(float x) {
  const float a = fminf(fabsf(x), 15.f);
  const float e = __expf(2.f * a);
  const float r = (e - 1.f) / (e + 1.f);
  return copysignf(r, x);
}
__device__ __forceinline__ int akw(int k) { return k + 4*(k/192); }
__device__ __forceinline__ int akr(int k) { return k + 4*(k/128); }

// cross-WG scalar ops: relaxed agent-scope atomics (L3 coherence point)
__device__ __forceinline__ void gst(float* p, float v) {
  __hip_atomic_store(p, v, __ATOMIC_RELAXED, __HIP_MEMORY_SCOPE_AGENT);
}
__device__ __forceinline__ void gst4(float* p, f32x4 v) {
  asm volatile("global_store_dwordx4 %0, %1, off sc0 sc1" :: "v"(p), "v"(v) : "memory");
}

// Tagged-dataflow sync: producer drains its data publishes (vmcnt ack = globally
// visible at L3), then stores its tag. Consumer spins until all 64 producer tags
// carry the current step, then issues data loads (service time > tag-observe
// time > data-visible time => safe). Tags start as 0xAAAAAAAA (poison) which is
// negative and never equals a phase value.
__device__ __forceinline__ void tag_store(int* tp, int v) {
  asm volatile("s_waitcnt vmcnt(0) lgkmcnt(0)" ::: "memory");
  __syncthreads();
  if (threadIdx.x == 0)
    __hip_atomic_store(tp, v, __ATOMIC_RELAXED, __HIP_MEMORY_SCOPE_AGENT);
}
__device__ __forceinline__ void tag_spin(const int* tags, int v) {
  if (threadIdx.x < 64) {   // 64 lanes poll 64 tag lines in parallel
    int sp = 0;
    for (;;) {
      const int t = __hip_atomic_load(&tags[threadIdx.x * 16], __ATOMIC_RELAXED,
                                      __HIP_MEMORY_SCOPE_AGENT);
      if (__all(t == v)) break;
      __builtin_amdgcn_s_sleep(2);   // throttle poll pressure on L3
      if (++sp > (1 << 14)) break;   // fail loud (wrong answer), never hang
    }
  }
  __syncthreads();
}
// fenced barrier — used ONCE after the weight fold (normal stores/loads of Wf)
__device__ __forceinline__ void barrier_fenced(int* cnt, int target) {
  __syncthreads();
  if (threadIdx.x == 0) {
    __threadfence();
    __hip_atomic_fetch_add(cnt, 1, __ATOMIC_RELAXED, __HIP_MEMORY_SCOPE_AGENT);
    int sp = 0;
    while (__hip_atomic_load(cnt, __ATOMIC_RELAXED, __HIP_MEMORY_SCOPE_AGENT) < target) {
      if (++sp > (1 << 20)) break;
    }
    __threadfence();
  }
  __syncthreads();
}

__global__ void __launch_bounds__(TB) nse_kernel(
    const float* __restrict__ x,
    const float* __restrict__ rW, const float* __restrict__ rU, const float* __restrict__ rb,
    const float* __restrict__ wW, const float* __restrict__ wU, const float* __restrict__ wb,
    const float* __restrict__ cW, const float* __restrict__ cb,
    float* __restrict__ out, float* __restrict__ ws)
{
  extern __shared__ float sm[];
  const int tid = threadIdx.x;
  const int w = blockIdx.x;
  const int g = w >> 6;        // 4 groups x 64 members; group owns batches 8g..8g+7
  const int m = w & 63;        // member owns d-cols [4m,4m+4) for all 8 batches,
                               // and mem rows [32*(m&7), +32) of batch (m>>3)
  const int b0 = g * 8;
  const int blm = m >> 3;
  const int isl = m & 7;
  const int bmy = b0 + blm;

  float* Wf   = ws + WS_WF;
  float* bfv  = ws + WS_BF;
  float* hpub = ws + WS_HP;
  float* par  = ws + WS_PAR;
  float* whp  = ws + WS_WHP;
  int*   bars = (int*)(ws + WS_BAR);
  int* tagsA  = &bars[g*1024];          // my group's A tags (one 64B line per WG)
  int* tagsB  = &bars[4096 + g*1024];
  int* myA    = &tagsA[m*16];
  int* myB    = &tagsB[m*16];
  int* lcnt   = &bars[8192];
  int* magic  = &bars[8192 + 32];

  // ---- legacy counter init (ws poisoned 0xAA every launch) ----
  if (w == 0 && tid == 0) {
    __hip_atomic_store(lcnt, 0, __ATOMIC_RELAXED, __HIP_MEMORY_SCOPE_AGENT);
    __hip_atomic_store(magic, 1357911, __ATOMIC_RELEASE, __HIP_MEMORY_SCOPE_AGENT);
  }
  if (tid == 0) {
    int sp = 0;
    while (__hip_atomic_load(magic, __ATOMIC_ACQUIRE, __HIP_MEMORY_SCOPE_AGENT) != 1357911) {
      if (++sp > (1 << 20)) break;
    }
  }
  __syncthreads();

  // ================= fold: Wf = cW @ wW (32k x 64n per WG), bf = cb@wW + wb =================
  {
    const int kt = w >> 4, nt = w & 15;
    const int r = tid >> 4, c4 = (tid & 15) * 4;
    float a0 = 0.f, a1 = 0.f, a2 = 0.f, a3 = 0.f;
    for (int jc = 0; jc < 512; jc += 32) {
      for (int u = tid; u < 1024; u += TB) {
        int rr = u >> 5, jj = u & 31;
        sm[rr*33 + jj] = cW[(32*kt + rr)*512 + jc + jj];
      }
      {
        int jj = tid >> 4, cc = (tid & 15) * 4;
        const f32x4 v = *(const f32x4*)&wW[(jc + jj)*1024 + 64*nt + cc];
        float* d = &sm[1056 + jj*68 + cc];
        d[0] = v.x; d[1] = v.y; d[2] = v.z; d[3] = v.w;
      }
      __syncthreads();
      #pragma unroll 8
      for (int j = 0; j < 32; j++) {
        const float a = sm[r*33 + j];
        const float* wv = &sm[1056 + j*68 + c4];
        a0 += a*wv[0]; a1 += a*wv[1]; a2 += a*wv[2]; a3 += a*wv[3];
      }
      __syncthreads();
    }
    float* d = &Wf[(32*kt + r)*1024 + 64*nt + c4];
    d[0] = a0; d[1] = a1; d[2] = a2; d[3] = a3;
  }
  if (w >= 16 && w < 32) {   // bias fold
    __syncthreads();
    const int base = (w - 16) * 64;
    const int c = tid & 63, jq = tid >> 6;
    float p = 0.f;
    for (int j = 64*jq; j < 64*jq + 64; j++) p += cb[j] * wW[j*1024 + base + c];
    sm[jq*68 + c] = p;
    __syncthreads();
    if (tid < 64) {
      float s = wb[base + tid];
      for (int j = 0; j < 8; j++) s += sm[j*68 + tid];
      bfv[base + tid] = s;
    }
  }
  barrier_fenced(lcnt, 256);

  // ================= init: stage weights, mem, x0, biases; zero state =================
  for (int u = tid; u < 3072; u += TB) {        // writer [Wf|wU] col slice (192-pad)
    const int k = u >> 2, gate = u & 3;
    const float* sp = (k < 512) ? &Wf[(size_t)k*1024 + gate*256 + 4*m]
                                : &wU[(size_t)(k-512)*1024 + gate*256 + 4*m];
    const f32x4 v = *(const f32x4*)sp;
    const int ik = akw(k);
    sm[O_WW + (gate*4+0)*S_WW + ik] = v.x;
    sm[O_WW + (gate*4+1)*S_WW + ik] = v.y;
    sm[O_WW + (gate*4+2)*S_WW + ik] = v.z;
    sm[O_WW + (gate*4+3)*S_WW + ik] = v.w;
  }
  for (int u = tid; u < 2048; u += TB) {        // reader [rW|rU] col slice (128-pad)
    const int k = u >> 2, gate = u & 3;
    const float* sp = (k < 256) ? &rW[(size_t)k*1024 + gate*256 + 4*m]
                                : &rU[(size_t)(k-256)*1024 + gate*256 + 4*m];
    const f32x4 v = *(const f32x4*)sp;
    const int ik = akr(k);
    sm[O_RW + (gate*4+0)*S_RW + ik] = v.x;
    sm[O_RW + (gate*4+1)*S_RW + ik] = v.y;
    sm[O_RW + (gate*4+2)*S_RW + ik] = v.z;
    sm[O_RW + (gate*4+3)*S_RW + ik] = v.w;
  }
  for (int u = tid; u < 2048; u += TB) {        // mem slice init = x[bmy][32*isl..][:]
    const int r = u >> 6, d4 = (u & 63) * 4;
    *(f32x4*)&sm[O_MEM + r*S_MEM + d4] =
        *(const f32x4*)&x[((size_t)bmy*TT + 32*isl + r)*DD + d4];
  }
  for (int u = tid; u < LDS_FLOATS - O_WACT; u += TB) sm[O_WACT + u] = 0.f;
  __syncthreads();
  {   // x_0
    const int bl = tid >> 6, d4 = (tid & 63) * 4;
    *(f32x4*)&sm[O_RACT + bl*S_RACT + akr(d4)] =
        *(const f32x4*)&x[(size_t)(b0+bl)*TT*DD + d4];
  }
  if (tid < 16) {
    const int gate = tid >> 2, dl = tid & 3;
    sm[O_WB + tid] = bfv[gate*256 + 4*m + dl];
    sm[O_RB + tid] = rb[gate*256 + 4*m + dl];
  }
  __syncthreads();

  // thread roles for the GEMVs
  const int q   = tid & 3;
  const int cl  = ((tid >> 4) & 3) + 4 * (tid >> 7);
  const int bl8 = ((tid >> 2) & 3) + 4 * ((tid >> 6) & 1);

  // ================= merged loop: reader step s (s<=255), writer step t=s-1 (s>=1) =================
  for (int s = 0; s <= TT; s++) {
    // ---- consume tagB(s-1): h_{s-1} + wh_{s-2} (one batched RT) ----
    if (s >= 1) {
      tag_spin(tagsB, s - 1);
      const int bl = tid >> 6, d4 = (tid & 63) * 4;
      f32x4 vh, vw;
      const float* ph = &hpub[(size_t)((s-1)&1)*8192 + (b0+bl)*256 + d4];
      const float* pw = &whp[(b0+bl)*256 + d4];
      asm volatile(
        "global_load_dwordx4 %0, %2, off sc0 sc1\n\t"
        "global_load_dwordx4 %1, %3, off sc0 sc1\n\t"
        "s_waitcnt vmcnt(0)"
        : "=&v"(vh), "=&v"(vw) : "v"(ph), "v"(pw) : "memory");
      *(f32x4*)&sm[O_RACT + bl*S_RACT + akr(256 + d4)] = vh;   // reader h-in / W1 o
      *(f32x4*)&sm[O_WACT + bl*S_WACT + akw(d4)]       = vh;   // writer GEMV o
      if (s >= 2)
        *(f32x4*)&sm[O_WACT + bl*S_WACT + akw(512 + d4)] = vw; // writer wh-in + mem upd
    }
    __syncthreads();

    // ---- W1 (s>=1): fused lazy mem-update (wh_{s-2}, z_{s-2}) + scores vs o_{s-1} ----
    if (s >= 1) {
      const int r = tid >> 4, tk = tid & 15;
      float* mrow = &sm[O_MEM + r*S_MEM + 16*tk];
      const float* orow = &sm[O_RACT + blm*S_RACT + akr(256 + 16*tk)];
      float acc = 0.f;
      if (s >= 2) {
        const float zr = sm[O_SE + r] * sm[O_RJ + blm*8 + isl];
        const float omz = 1.f - zr;
        const float* hrow = &sm[O_WACT + blm*S_WACT + akw(512 + 16*tk)];
        #pragma unroll
        for (int i2 = 0; i2 < 16; i2 += 4) {
          f32x4 mv = *(f32x4*)(mrow + i2);
          const f32x4 hv = *(const f32x4*)(hrow + i2);
          const f32x4 ov = *(const f32x4*)(orow + i2);
          mv.x = mv.x*omz + hv.x*zr;  mv.y = mv.y*omz + hv.y*zr;
          mv.z = mv.z*omz + hv.z*zr;  mv.w = mv.w*omz + hv.w*zr;
          *(f32x4*)(mrow + i2) = mv;
          acc += mv.x*ov.x + mv.y*ov.y + mv.z*ov.z + mv.w*ov.w;
        }
      } else {
        #pragma unroll
        for (int i2 = 0; i2 < 16; i2 += 4) {
          const f32x4 mv = *(const f32x4*)(mrow + i2);
          const f32x4 ov = *(const f32x4*)(orow + i2);
          acc += mv.x*ov.x + mv.y*ov.y + mv.z*ov.z + mv.w*ov.w;
        }
      }
      acc += __shfl_xor(acc, 1, 64); acc += __shfl_xor(acc, 2, 64);
      acc += __shfl_xor(acc, 4, 64); acc += __shfl_xor(acc, 8, 64);
      if (tk == 0) sm[O_SS + r] = acc;
    }
    __syncthreads();
    if (s >= 1 && tid < 32) {   // local softmax over my 32 rows; publish (max,sum)
      const float sc = sm[O_SS + tid];
      float mx = sc;
      mx = fmaxf(mx, __shfl_xor(mx, 1, 64)); mx = fmaxf(mx, __shfl_xor(mx, 2, 64));
      mx = fmaxf(mx, __shfl_xor(mx, 4, 64)); mx = fmaxf(mx, __shfl_xor(mx, 8, 64));
      mx = fmaxf(mx, __shfl_xor(mx, 16, 64));
      const float e = __expf(sc - mx);
      float su = e;
      su += __shfl_xor(su, 1, 64); su += __shfl_xor(su, 2, 64); su += __shfl_xor(su, 4, 64);
      su += __shfl_xor(su, 8, 64); su += __shfl_xor(su, 16, 64);
      sm[O_SE + tid] = e;
      if (tid == 0) {
        gst(&par[((size_t)bmy*8 + isl)*PS + 256], mx);
        gst(&par[((size_t)bmy*8 + isl)*PS + 257], su);
      }
    }
    __syncthreads();
    // ---- W2 (s>=1): P_isl[d] = sum_r e_r mem[r][d]; vector publish; tagA ----
    if (s >= 1) {
      const int dblk = tid >> 3, rh = tid & 7;
      f32x4 p; p.x = 0.f; p.y = 0.f; p.z = 0.f; p.w = 0.f;
      #pragma unroll
      for (int i = 0; i < 4; i++) {
        const int rr = 4*rh + i;
        const float e = sm[O_SE + rr];
        const f32x4 mv = *(const f32x4*)&sm[O_MEM + rr*S_MEM + 4*dblk];
        p.x += e*mv.x; p.y += e*mv.y; p.z += e*mv.z; p.w += e*mv.w;
      }
      p.x += __shfl_xor(p.x,1,64); p.x += __shfl_xor(p.x,2,64); p.x += __shfl_xor(p.x,4,64);
      p.y += __shfl_xor(p.y,1,64); p.y += __shfl_xor(p.y,2,64); p.y += __shfl_xor(p.y,4,64);
      p.z += __shfl_xor(p.z,1,64); p.z += __shfl_xor(p.z,2,64); p.z += __shfl_xor(p.z,4,64);
      p.w += __shfl_xor(p.w,1,64); p.w += __shfl_xor(p.w,2,64); p.w += __shfl_xor(p.w,4,64);
      if (rh == 0) gst4(&par[((size_t)bmy*8 + isl)*PS + 4*dblk], p);
      tag_store(myA, s);
    } else {
      __syncthreads();   // keep wave phase aligned (tag_store has a syncthreads)
    }

    // ---- slack: reader GEMV + LSTM + h publish (covered later by tagB) ----
    if (s <= TT-1) {
      const float* wr = &sm[O_RW + cl*S_RW + 132*q];
      const float* ar = &sm[O_RACT + bl8*S_RACT + 132*q];
      float acc = 0.f;
      #pragma unroll
      for (int kk = 0; kk < 128; kk += 4) {
        const f32x4 wv = *(const f32x4*)(wr + kk);
        const f32x4 av = *(const f32x4*)(ar + kk);
        acc += wv.x*av.x + wv.y*av.y + wv.z*av.z + wv.w*av.w;
      }
      acc += __shfl_xor(acc, 1, 64);
      acc += __shfl_xor(acc, 2, 64);
      if (q == 0) sm[O_RZ + bl8*20 + cl] = acc + sm[O_RB + cl];
    }
    __syncthreads();
    if (s <= TT-1 && tid < 32) {
      const int bl = tid >> 2, dl = tid & 3;
      const float zi = sm[O_RZ + bl*20 + dl];
      const float zf = sm[O_RZ + bl*20 + 4 + dl];
      const float zg = sm[O_RZ + bl*20 + 8 + dl];
      const float zo = sm[O_RZ + bl*20 + 12 + dl];
      const float cn = hsig(zf)*sm[O_RC + tid] + hsig(zi)*ftanh(zg);
      sm[O_RC + tid] = cn;
      gst(&hpub[(size_t)(s&1)*8192 + (b0+bl)*256 + 4*m + dl], hsig(zo)*ftanh(cn));
    }

    if (s >= 1) {
      tag_spin(tagsA, s);
      // ---- combine: ONE RT for 8 P-slices + (max,sum) ----
      const int bl = tid >> 6, d4 = (tid & 63) * 4;
      f32x4 v0,v1,v2,v3,v4,v5,v6,v7;
      float msv;
      {
        const float* p0 = &par[((size_t)(b0+bl)*8 + 0)*PS + d4];
        const float* p4 = p0 + 4*PS;
        const int idx = tid & 127;
        const float* msp = &par[((size_t)(b0 + (idx>>4))*8 + ((idx>>1)&7))*PS + 256 + (idx&1)];
        asm volatile(
          "global_load_dwordx4 %0, %9, off sc0 sc1\n\t"
          "global_load_dwordx4 %1, %9, off offset:1040 sc0 sc1\n\t"
          "global_load_dwordx4 %2, %9, off offset:2080 sc0 sc1\n\t"
          "global_load_dwordx4 %3, %9, off offset:3120 sc0 sc1\n\t"
          "global_load_dwordx4 %4, %10, off sc0 sc1\n\t"
          "global_load_dwordx4 %5, %10, off offset:1040 sc0 sc1\n\t"
          "global_load_dwordx4 %6, %10, off offset:2080 sc0 sc1\n\t"
          "global_load_dwordx4 %7, %10, off offset:3120 sc0 sc1\n\t"
          "global_load_dword   %8, %11, off sc0 sc1\n\t"
          "s_waitcnt vmcnt(0)"
          : "=&v"(v0),"=&v"(v1),"=&v"(v2),"=&v"(v3),
            "=&v"(v4),"=&v"(v5),"=&v"(v6),"=&v"(v7),"=&v"(msv)
          : "v"(p0), "v"(p4), "v"(msp) : "memory");
      }
      if (tid < 128) sm[O_MS + tid] = msv;
      __syncthreads();
      if (tid < 8) {
        const int bl2 = tid;
        float M = sm[O_MS + bl2*16];
        for (int j = 1; j < 8; j++) M = fmaxf(M, sm[O_MS + bl2*16 + 2*j]);
        float tot = 0.f, f0[8];
        for (int j = 0; j < 8; j++) {
          f0[j] = __expf(sm[O_MS + bl2*16 + 2*j] - M);
          tot += f0[j] * sm[O_MS + bl2*16 + 2*j + 1];
        }
        const float inv = 1.f / tot;
        for (int j = 0; j < 8; j++) sm[O_RJ + bl2*8 + j] = f0[j]*inv;
      }
      __syncthreads();
      {
        const float* rj = &sm[O_RJ + bl*8];
        f32x4 a;
        a.x = rj[0]*v0.x + rj[1]*v1.x + rj[2]*v2.x + rj[3]*v3.x
            + rj[4]*v4.x + rj[5]*v5.x + rj[6]*v6.x + rj[7]*v7.x;
        a.y = rj[0]*v0.y + rj[1]*v1.y + rj[2]*v2.y + rj[3]*v3.y
            + rj[4]*v4.y + rj[5]*v5.y + rj[6]*v6.y + rj[7]*v7.y;
        a.z = rj[0]*v0.z + rj[1]*v1.z + rj[2]*v2.z + rj[3]*v3.z
            + rj[4]*v4.z + rj[5]*v5.z + rj[6]*v6.z + rj[7]*v7.z;
        a.w = rj[0]*v0.w + rj[1]*v1.w + rj[2]*v2.w + rj[3]*v3.w
            + rj[4]*v4.w + rj[5]*v5.w + rj[6]*v6.w + rj[7]*v7.w;
        *(f32x4*)&sm[O_WACT + bl*S_WACT + akw(256 + d4)] = a;
      }
      __syncthreads();
      // ---- writer gates GEMV (single ordered pass, R3 numerics) ----
      {
        const float* wr = &sm[O_WW + cl*S_WW + 196*q];
        const float* ar = &sm[O_WACT + bl8*S_WACT + 196*q];
        float acc = 0.f;
        #pragma unroll 8
        for (int kk = 0; kk < 192; kk += 4) {
          const f32x4 wv = *(const f32x4*)(wr + kk);
          const f32x4 av = *(const f32x4*)(ar + kk);
          acc += wv.x*av.x + wv.y*av.y + wv.z*av.z + wv.w*av.w;
        }
        acc += __shfl_xor(acc, 1, 64);
        acc += __shfl_xor(acc, 2, 64);
        if (q == 0) sm[O_WZ + bl8*20 + cl] = acc + sm[O_WB + cl];
      }
      __syncthreads();
      if (tid < 32) {   // writer LSTM update + publish wh (or out at last step)
        const int bl2 = tid >> 2, dl = tid & 3;
        const float zi = sm[O_WZ + bl2*20 + dl];
        const float zf = sm[O_WZ + bl2*20 + 4 + dl];
        const float zg = sm[O_WZ + bl2*20 + 8 + dl];
        const float zo = sm[O_WZ + bl2*20 + 12 + dl];
        const float cn = hsig(zf)*sm[O_WC + tid] + hsig(zi)*ftanh(zg);
        sm[O_WC + tid] = cn;
        const float hn = hsig(zo)*ftanh(cn);
        if (s == TT) out[(b0+bl2)*256 + 4*m + dl] = hn;
        else         gst(&whp[(b0+bl2)*256 + 4*m + dl], hn);
      }
    }
    if (s == TT) break;                        // out stored; nothing left to sync
    tag_store(myB, s);                         // covers wh_{s-1} + h_s publishes
    if (s <= TT-2) {   // slack: stage x_{s+1}
      const int bl = tid >> 6, d4 = (tid & 63) * 4;
      *(f32x4*)&sm[O_RACT + bl*S_RACT + akr(d4)] =
          *(const f32x4*)&x[((size_t)(b0+bl)*TT + s + 1)*DD + d4];
    }
  }
}

extern "C" void kernel_launch(void* const* d_in, const int* in_sizes, int n_in,
                              void* d_out, int out_size, void* d_ws, size_t ws_size,
                              hipStream_t stream) {
  (void)in_sizes; (void)n_in;
  if (ws_size < (size_t)WS_FLOATS * 4u) {   // loud failure instead of corruption
    hipMemsetAsync(d_out, 0, (size_t)out_size * 4u, stream);
    return;
  }
  const float* x  = (const float*)d_in[0];
  const float* rW = (const float*)d_in[1];
  const float* rU = (const float*)d_in[2];
  const float* rb = (const float*)d_in[3];
  const float* wW = (const float*)d_in[4];
  const float* wU = (const float*)d_in[5];
  const float* wb = (const float*)d_in[6];
  const float* cW = (const float*)d_in[7];
  const float* cb = (const float*)d_in[8];
  float* out = (float*)d_out;
  float* ws  = (float*)d_ws;

  hipFuncSetAttribute((const void*)nse_kernel,
                      hipFuncAttributeMaxDynamicSharedMemorySize, DYN_LDS_BYTES);

  void* args[] = { (void*)&x, (void*)&rW, (void*)&rU, (void*)&rb,
                   (void*)&wW, (void*)&wU, (void*)&wb, (void*)&cW, (void*)&cb,
                   (void*)&out, (void*)&ws };
  hipError_t err = hipLaunchCooperativeKernel((const void*)nse_kernel,
                                              dim3(256), dim3(TB), args,
                                              DYN_LDS_BYTES, stream);
  if (err != hipSuccess) {
    nse_kernel<<<dim3(256), dim3(TB), DYN_LDS_BYTES, stream>>>(
        x, rW, rU, rb, wW, wU, wb, cW, cb, out, ws);
  }
}